// Round 2
// baseline (210.951 us; speedup 1.0000x reference)
//
#include <hip/hip_runtime.h>
#include <math.h>

#define DEV __device__ __forceinline__

DEV float dot4(float4 w, float4 x) {
    float s = 0.f;
    s = fmaf(w.x, x.x, s); s = fmaf(w.y, x.y, s);
    s = fmaf(w.z, x.z, s); s = fmaf(w.w, x.w, s);
    return s;
}

DEV float wave_reduce(float v) {
    for (int off = 32; off > 0; off >>= 1) v += __shfl_down(v, off);
    return v;
}

// ---- workspace layout (float offsets; all 16B-aligned) ----
#define WS_PRIOR   0      // 32   m1x_prior
#define WS_DY      32     // 32   y - m1y
#define WS_FC5     64     // 160  out_FC5
#define WS_XSIG    224    // 1184 [out_Q | out_FC6]
#define WS_INFC2   1408   // 2048 [out_Sigma | out_S]
#define WS_XS      3456   // 1344 [out_FC1 | out_FC7]
#define WS_FC2OUT  4800   // 1024 out_FC2 (= KG flat)
#define WS_HID     5824   // 81920 relu(FC2_w1 @ in_FC2 + b1)
// total = 87744 floats = 350,976 bytes of d_ws

// K1: priors, normalized feature diffs, FC5/FC6/FC7 — one block, 320 threads
__global__ void k_small(const float* __restrict__ y, const float* __restrict__ post,
                        const float* __restrict__ post_prev, const float* __restrict__ prior_prev,
                        const float* __restrict__ y_prev,
                        const float* __restrict__ F, const float* __restrict__ Hm,
                        const float* __restrict__ fc5w, const float* __restrict__ fc5b,
                        const float* __restrict__ fc6w, const float* __restrict__ fc6b,
                        const float* __restrict__ fc7w, const float* __restrict__ fc7b,
                        float* __restrict__ ws) {
    __shared__ float s_post[32], s_prior[32], s_m1y[32];
    __shared__ float s_diff[4][32];
    __shared__ float s_inv[4];
    __shared__ float s_evol[32], s_upd[32], s_obs[64];
    int tid = threadIdx.x;
    if (tid < 32) s_post[tid] = post[tid];
    __syncthreads();
    if (tid < 32) {
        float a = 0.f;
        for (int j = 0; j < 32; ++j) a = fmaf(F[tid * 32 + j], s_post[j], a);
        s_prior[tid] = a;
        ws[WS_PRIOR + tid] = a;
    }
    __syncthreads();
    if (tid < 32) {
        float a = 0.f;
        for (int j = 0; j < 32; ++j) a = fmaf(Hm[tid * 32 + j], s_prior[j], a);
        s_m1y[tid] = a;
    }
    __syncthreads();
    if (tid < 128) {
        int v = tid >> 5, j = tid & 31;
        float d;
        if (v == 0)      d = y[j] - y_prev[j];
        else if (v == 1) d = y[j] - s_m1y[j];
        else if (v == 2) d = post[j] - post_prev[j];
        else             d = post[j] - prior_prev[j];
        s_diff[v][j] = d;
    }
    __syncthreads();
    if (tid < 4) {
        float s = 0.f;
        for (int j = 0; j < 32; ++j) s += s_diff[tid][j] * s_diff[tid][j];
        s_inv[tid] = 1.0f / fmaxf(sqrtf(s), 1e-12f);
    }
    __syncthreads();
    if (tid < 128) {
        int v = tid >> 5, j = tid & 31;
        float nd = s_diff[v][j] * s_inv[v];
        if (v == 0)      s_obs[j] = nd;
        else if (v == 1) { s_obs[32 + j] = nd; ws[WS_DY + j] = s_diff[1][j]; }
        else if (v == 2) s_evol[j] = nd;
        else             s_upd[j] = nd;
    }
    __syncthreads();
    if (tid < 160) {
        float a = fc5b[tid];
        for (int j = 0; j < 32; ++j) a = fmaf(fc5w[tid * 32 + j], s_evol[j], a);
        ws[WS_FC5 + tid] = fmaxf(a, 0.f);
    } else {
        int i = tid - 160;
        float a = fc6b[i];
        for (int j = 0; j < 32; ++j) a = fmaf(fc6w[i * 32 + j], s_upd[j], a);
        ws[WS_XSIG + 1024 + i] = fmaxf(a, 0.f);     // out_FC6 after out_Q
    }
    {
        float a = fc7b[tid];
        for (int j = 0; j < 64; ++j) a = fmaf(fc7w[tid * 64 + j], s_obs[j], a);
        ws[WS_XS + 1024 + tid] = fmaxf(a, 0.f);     // out_FC7 after out_FC1
    }
}

// Generic single-step GRU (hidden = 1024, gate order r,z,n): one wave per output element.
__global__ void k_gru(const float* __restrict__ x, const float* __restrict__ h,
                      const float* __restrict__ Wih, const float* __restrict__ Whh,
                      const float* __restrict__ bih, const float* __restrict__ bhh,
                      float* __restrict__ out, int Kx) {
    int wid = (blockIdx.x * blockDim.x + threadIdx.x) >> 6;
    int lane = threadIdx.x & 63;
    int K4 = Kx >> 2;
    const float4* x4 = (const float4*)x;
    const float4* W0 = (const float4*)Wih + (size_t)wid * K4;
    float ai0 = 0.f, ai1 = 0.f, ai2 = 0.f;
    for (int k = lane; k < K4; k += 64) {
        float4 xv = x4[k];
        ai0 += dot4(W0[k], xv);
        ai1 += dot4(W0[(size_t)1024 * K4 + k], xv);
        ai2 += dot4(W0[(size_t)2048 * K4 + k], xv);
    }
    const float4* h4 = (const float4*)h;                 // 256 float4 = 1024 f32
    const float4* V0 = (const float4*)Whh + (size_t)wid * 256;
    float ah0 = 0.f, ah1 = 0.f, ah2 = 0.f;
    for (int k = lane; k < 256; k += 64) {
        float4 hv = h4[k];
        ah0 += dot4(V0[k], hv);
        ah1 += dot4(V0[(size_t)1024 * 256 + k], hv);
        ah2 += dot4(V0[(size_t)2048 * 256 + k], hv);
    }
    for (int off = 32; off > 0; off >>= 1) {
        ai0 += __shfl_down(ai0, off); ai1 += __shfl_down(ai1, off); ai2 += __shfl_down(ai2, off);
        ah0 += __shfl_down(ah0, off); ah1 += __shfl_down(ah1, off); ah2 += __shfl_down(ah2, off);
    }
    if (lane == 0) {
        float gr = ai0 + bih[wid]        + ah0 + bhh[wid];
        float gz = ai1 + bih[wid + 1024] + ah1 + bhh[wid + 1024];
        float r = 1.f / (1.f + expf(-gr));
        float z = 1.f / (1.f + expf(-gz));
        float n = tanhf(ai2 + bih[wid + 2048] + r * (ah2 + bhh[wid + 2048]));
        out[wid] = (1.f - z) * n + z * h[wid];
    }
}

// Wave-per-row matvec + ReLU: f32 W [rows x K], f32 x, f32 b, f32 out.
__global__ void k_matvec_relu(const float* __restrict__ W, const float* __restrict__ x,
                              const float* __restrict__ b, float* __restrict__ out, int K) {
    int wid = (blockIdx.x * blockDim.x + threadIdx.x) >> 6;
    int lane = threadIdx.x & 63;
    int K4 = K >> 2;
    const float4* w4 = (const float4*)W + (size_t)wid * K4;
    const float4* x4 = (const float4*)x;
    float a = 0.f;
    for (int k = lane; k < K4; k += 64) {
        a += dot4(w4[k], x4[k]);
    }
    a = wave_reduce(a);
    if (lane == 0) out[wid] = fmaxf(a + b[wid], 0.f);
}

// Block-per-row matvec (no ReLU) for the long-K second FC2 layer.
__global__ void k_matvec_big(const float* __restrict__ W, const float* __restrict__ x,
                             const float* __restrict__ b, float* __restrict__ out, int K) {
    int row = blockIdx.x;
    int tid = threadIdx.x;   // 256
    int K4 = K >> 2;
    const float4* w4 = (const float4*)W + (size_t)row * K4;
    const float4* x4 = (const float4*)x;
    float a = 0.f;
    for (int k = tid; k < K4; k += 256) {
        a += dot4(w4[k], x4[k]);
    }
    a = wave_reduce(a);
    __shared__ float s[4];
    if ((tid & 63) == 0) s[tid >> 6] = a;
    __syncthreads();
    if (tid == 0) out[row] = s[0] + s[1] + s[2] + s[3] + b[row];
}

// Epilogue: m1x_new = m1x_prior + KG @ dy ; write f32 output.
__global__ void k_final(const float* __restrict__ ws, float* __restrict__ out) {
    int i = threadIdx.x;   // 32
    const float* kg = ws + WS_FC2OUT;
    const float* dy = ws + WS_DY;
    float a = ws[WS_PRIOR + i];
    for (int j = 0; j < 32; ++j) a = fmaf(kg[i * 32 + j], dy[j], a);
    out[i] = a;
}

extern "C" void kernel_launch(void* const* d_in, const int* in_sizes, int n_in,
                              void* d_out, int out_size, void* d_ws, size_t ws_size,
                              hipStream_t stream) {
    const float* y          = (const float*)d_in[0];
    const float* post       = (const float*)d_in[1];
    const float* post_prev  = (const float*)d_in[2];
    const float* prior_prev = (const float*)d_in[3];
    const float* y_prev     = (const float*)d_in[4];
    const float* h_Q        = (const float*)d_in[5];
    const float* h_Sigma    = (const float*)d_in[6];
    const float* h_S        = (const float*)d_in[7];
    const float* F          = (const float*)d_in[8];
    const float* Hm         = (const float*)d_in[9];
    const float* FC5_w      = (const float*)d_in[10];
    const float* FC5_b      = (const float*)d_in[11];
    const float* FC6_w      = (const float*)d_in[12];
    const float* FC6_b      = (const float*)d_in[13];
    const float* FC7_w      = (const float*)d_in[14];
    const float* FC7_b      = (const float*)d_in[15];
    const float* GQ_Wih     = (const float*)d_in[16];
    const float* GQ_Whh     = (const float*)d_in[17];
    const float* GQ_bih     = (const float*)d_in[18];
    const float* GQ_bhh     = (const float*)d_in[19];
    const float* GS_Wih     = (const float*)d_in[20];
    const float* GS_Whh     = (const float*)d_in[21];
    const float* GS_bih     = (const float*)d_in[22];
    const float* GS_bhh     = (const float*)d_in[23];
    const float* GU_Wih     = (const float*)d_in[24];
    const float* GU_Whh     = (const float*)d_in[25];
    const float* GU_bih     = (const float*)d_in[26];
    const float* GU_bhh     = (const float*)d_in[27];
    const float* FC1_w      = (const float*)d_in[28];
    const float* FC1_b      = (const float*)d_in[29];
    const float* FC2_w1     = (const float*)d_in[30];
    const float* FC2_b1     = (const float*)d_in[31];
    const float* FC2_w2     = (const float*)d_in[32];
    const float* FC2_b2     = (const float*)d_in[33];
    // d_in[34..37] = FC3/FC4 weights: dead code (only feed the deleted out_FC4)
    // d_in[38] = fix_H_flag (always 1 in setup; linear-H path)

    float* ws = (float*)d_ws;

    // 1) prologue: priors, normalized diffs, FC5/FC6/FC7
    k_small<<<1, 320, 0, stream>>>(y, post, post_prev, prior_prev, y_prev, F, Hm,
                                   FC5_w, FC5_b, FC6_w, FC6_b, FC7_w, FC7_b, ws);
    // 2) GRU_Q: x = out_FC5 (160) -> out_Q at XSIG[0:1024)
    k_gru<<<256, 256, 0, stream>>>(ws + WS_FC5, h_Q, GQ_Wih, GQ_Whh, GQ_bih, GQ_bhh,
                                   ws + WS_XSIG, 160);
    // 3) GRU_Sigma: x = [out_Q|out_FC6] (1184) -> out_Sigma at INFC2[0:1024)
    k_gru<<<256, 256, 0, stream>>>(ws + WS_XSIG, h_Sigma, GS_Wih, GS_Whh, GS_bih, GS_bhh,
                                   ws + WS_INFC2, 1184);
    // 4) FC1: 1024x1024 + ReLU -> out_FC1 at XS[0:1024)
    k_matvec_relu<<<256, 256, 0, stream>>>(FC1_w, ws + WS_INFC2, FC1_b, ws + WS_XS, 1024);
    // 5) GRU_S: x = [out_FC1|out_FC7] (1344) -> out_S at INFC2[1024:2048)
    k_gru<<<256, 256, 0, stream>>>(ws + WS_XS, h_S, GU_Wih, GU_Whh, GU_bih, GU_bhh,
                                   ws + WS_INFC2 + 1024, 1344);
    // 6) FC2 layer 1: 81920x2048 + ReLU -> hidden
    k_matvec_relu<<<20480, 256, 0, stream>>>(FC2_w1, ws + WS_INFC2, FC2_b1, ws + WS_HID, 2048);
    // 7) FC2 layer 2: 1024x81920 -> out_FC2 (= KG flat)
    k_matvec_big<<<1024, 256, 0, stream>>>(FC2_w2, ws + WS_HID, FC2_b2, ws + WS_FC2OUT, 81920);
    // 8) epilogue: prior + KG @ dy -> f32 out
    k_final<<<1, 32, 0, stream>>>(ws, (float*)d_out);
}

// Round 3
// 205.632 us; speedup vs baseline: 1.0259x; 1.0259x over previous
//
#include <hip/hip_runtime.h>
#include <math.h>

#define DEV __device__ __forceinline__

DEV float dot4(float4 w, float4 x) {
    float s = 0.f;
    s = fmaf(w.x, x.x, s); s = fmaf(w.y, x.y, s);
    s = fmaf(w.z, x.z, s); s = fmaf(w.w, x.w, s);
    return s;
}

DEV float wave_reduce(float v) {          // full 64-lane sum -> lane 0
    for (int off = 32; off > 0; off >>= 1) v += __shfl_down(v, off);
    return v;
}
DEV float reduce32(float v) {             // sum within each 32-lane half
    for (int off = 16; off > 0; off >>= 1) v += __shfl_xor(v, off);
    return v;
}

// ---- workspace layout (float offsets; all 16B-aligned) ----
#define WS_Q      0        // 1024  out_Q
#define WS_SIG    1024     // 1024  out_Sigma   (start of in_FC2)
#define WS_S      2048     // 1024  out_S       (contiguous with SIG)
#define WS_FC1    3072     // 1024  out_FC1
#define WS_HID    4096     // 81920 relu(FC2_w1 @ in_FC2 + b1)
#define WS_KG     86016    // 1024  out_FC2 (= KG flat)
// total = 87040 floats = 348,160 bytes

// ---------------- GRU gate combine (shared tail) ----------------
DEV void gru_tail(int wid, int lane,
                  float ai0, float ai1, float ai2, float ah0, float ah1, float ah2,
                  const float* __restrict__ bih, const float* __restrict__ bhh,
                  const float* __restrict__ h, float* __restrict__ out) {
    ai0 = wave_reduce(ai0); ai1 = wave_reduce(ai1); ai2 = wave_reduce(ai2);
    ah0 = wave_reduce(ah0); ah1 = wave_reduce(ah1); ah2 = wave_reduce(ah2);
    if (lane == 0) {
        float gr = ai0 + bih[wid]        + ah0 + bhh[wid];
        float gz = ai1 + bih[wid + 1024] + ah1 + bhh[wid + 1024];
        float r = 1.f / (1.f + expf(-gr));
        float z = 1.f / (1.f + expf(-gz));
        float n = tanhf(ai2 + bih[wid + 2048] + r * (ah2 + bhh[wid + 2048]));
        out[wid] = (1.f - z) * n + z * h[wid];
    }
}

// Whh part: hidden=1024, K4=256, 4 unrolled iters
DEV void gru_hh(int wid, int lane, const float* __restrict__ Whh, const float* __restrict__ h,
                float& ah0, float& ah1, float& ah2) {
    const float4* V = (const float4*)Whh;
    const float4* v0 = V + (size_t)wid * 256;
    const float4* v1 = V + (size_t)(1024 + wid) * 256;
    const float4* v2 = V + (size_t)(2048 + wid) * 256;
    const float4* h4 = (const float4*)h;
#pragma unroll
    for (int i = 0; i < 4; ++i) {
        int k = lane + (i << 6);
        float4 hv = h4[k];
        ah0 += dot4(v0[k], hv); ah1 += dot4(v1[k], hv); ah2 += dot4(v2[k], hv);
    }
}

// -------- GRU_Q: x = relu(FC5_w @ normalize(post - post_prev) + b)  (K=160) --------
__global__ void k_gru_q(const float* __restrict__ post, const float* __restrict__ post_prev,
                        const float* __restrict__ fc5w, const float* __restrict__ fc5b,
                        const float* __restrict__ h,
                        const float* __restrict__ Wih, const float* __restrict__ Whh,
                        const float* __restrict__ bih, const float* __restrict__ bhh,
                        float* __restrict__ out) {
    __shared__ __align__(16) float sx[160];
    __shared__ float sd[32];
    __shared__ float sinv;
    int t = threadIdx.x;
    if (t < 32) sd[t] = post[t] - post_prev[t];
    __syncthreads();
    if (t < 64) {
        float d = (t < 32) ? sd[t] * sd[t] : 0.f;
        d = wave_reduce(d);
        if (t == 0) sinv = 1.f / fmaxf(sqrtf(d), 1e-12f);
    }
    __syncthreads();
    if (t < 160) {
        float a = 0.f;
#pragma unroll
        for (int j = 0; j < 32; ++j) a = fmaf(fc5w[t * 32 + j], sd[j], a);
        sx[t] = fmaxf(fmaf(a, sinv, fc5b[t]), 0.f);
    }
    __syncthreads();

    int wid = (blockIdx.x << 2) + (t >> 6);
    int lane = t & 63;
    const float4* W = (const float4*)Wih;       // rows of 40 float4
    const float4* sx4 = (const float4*)sx;
    float ai0 = 0.f, ai1 = 0.f, ai2 = 0.f, ah0 = 0.f, ah1 = 0.f, ah2 = 0.f;
    if (lane < 40) {
        float4 xv = sx4[lane];
        ai0 = dot4(W[(size_t)wid * 40 + lane], xv);
        ai1 = dot4(W[(size_t)(1024 + wid) * 40 + lane], xv);
        ai2 = dot4(W[(size_t)(2048 + wid) * 40 + lane], xv);
    }
    gru_hh(wid, lane, Whh, h, ah0, ah1, ah2);
    gru_tail(wid, lane, ai0, ai1, ai2, ah0, ah1, ah2, bih, bhh, h, out);
}

// -------- GRU_Sigma: x = [out_Q (1024, ws) | relu(FC6 @ normalize(post-prior_prev))] (K=1184) --------
__global__ void k_gru_sigma(const float* __restrict__ xq,
                            const float* __restrict__ post, const float* __restrict__ prior_prev,
                            const float* __restrict__ fc6w, const float* __restrict__ fc6b,
                            const float* __restrict__ h,
                            const float* __restrict__ Wih, const float* __restrict__ Whh,
                            const float* __restrict__ bih, const float* __restrict__ bhh,
                            float* __restrict__ out) {
    __shared__ __align__(16) float sx[160];
    __shared__ float sd[32];
    __shared__ float sinv;
    int t = threadIdx.x;
    if (t < 32) sd[t] = post[t] - prior_prev[t];
    __syncthreads();
    if (t < 64) {
        float d = (t < 32) ? sd[t] * sd[t] : 0.f;
        d = wave_reduce(d);
        if (t == 0) sinv = 1.f / fmaxf(sqrtf(d), 1e-12f);
    }
    __syncthreads();
    if (t < 160) {
        float a = 0.f;
#pragma unroll
        for (int j = 0; j < 32; ++j) a = fmaf(fc6w[t * 32 + j], sd[j], a);
        sx[t] = fmaxf(fmaf(a, sinv, fc6b[t]), 0.f);
    }
    __syncthreads();

    int wid = (blockIdx.x << 2) + (t >> 6);
    int lane = t & 63;
    const float4* W = (const float4*)Wih;       // rows of 296 float4
    const float4* w0 = W + (size_t)wid * 296;
    const float4* w1 = W + (size_t)(1024 + wid) * 296;
    const float4* w2 = W + (size_t)(2048 + wid) * 296;
    const float4* q4 = (const float4*)xq;
    const float4* sx4 = (const float4*)sx;
    float ai0 = 0.f, ai1 = 0.f, ai2 = 0.f, ah0 = 0.f, ah1 = 0.f, ah2 = 0.f;
#pragma unroll
    for (int i = 0; i < 4; ++i) {
        int k = lane + (i << 6);
        float4 xv = q4[k];
        ai0 += dot4(w0[k], xv); ai1 += dot4(w1[k], xv); ai2 += dot4(w2[k], xv);
    }
    if (lane < 40) {
        int k = 256 + lane;
        float4 xv = sx4[lane];
        ai0 += dot4(w0[k], xv); ai1 += dot4(w1[k], xv); ai2 += dot4(w2[k], xv);
    }
    gru_hh(wid, lane, Whh, h, ah0, ah1, ah2);
    gru_tail(wid, lane, ai0, ai1, ai2, ah0, ah1, ah2, bih, bhh, h, out);
}

// -------- GRU_S: x = [out_FC1 (1024, ws) | relu(FC7 @ [obs_diff|innov_diff])] (K=1344) --------
__global__ void k_gru_s(const float* __restrict__ xfc1,
                        const float* __restrict__ y, const float* __restrict__ y_prev,
                        const float* __restrict__ post,
                        const float* __restrict__ F, const float* __restrict__ Hm,
                        const float* __restrict__ fc7w, const float* __restrict__ fc7b,
                        const float* __restrict__ h,
                        const float* __restrict__ Wih, const float* __restrict__ Whh,
                        const float* __restrict__ bih, const float* __restrict__ bhh,
                        float* __restrict__ out) {
    __shared__ __align__(16) float sx[320];
    __shared__ float sprior[32];
    __shared__ float sd[2][32];
    __shared__ float sinv[2];
    int t = threadIdx.x;
    if (t < 32) {
        float p = 0.f;
#pragma unroll
        for (int j = 0; j < 32; ++j) p = fmaf(F[t * 32 + j], post[j], p);
        sprior[t] = p;
        sd[0][t] = y[t] - y_prev[t];
    }
    __syncthreads();
    if (t < 32) {
        float m = 0.f;
#pragma unroll
        for (int j = 0; j < 32; ++j) m = fmaf(Hm[t * 32 + j], sprior[j], m);
        sd[1][t] = y[t] - m;
    }
    __syncthreads();
    if (t < 64) {
        int g = t >> 5, j = t & 31;
        float d = sd[g][j];
        float s = reduce32(d * d);
        if (j == 0) sinv[g] = 1.f / fmaxf(sqrtf(s), 1e-12f);
    }
    __syncthreads();
    for (int r = t; r < 320; r += 256) {
        float a0 = 0.f, a1 = 0.f;
#pragma unroll
        for (int j = 0; j < 32; ++j) {
            a0 = fmaf(fc7w[r * 64 + j], sd[0][j], a0);
            a1 = fmaf(fc7w[r * 64 + 32 + j], sd[1][j], a1);
        }
        sx[r] = fmaxf(a0 * sinv[0] + a1 * sinv[1] + fc7b[r], 0.f);
    }
    __syncthreads();

    int wid = (blockIdx.x << 2) + (t >> 6);
    int lane = t & 63;
    const float4* W = (const float4*)Wih;       // rows of 336 float4
    const float4* w0 = W + (size_t)wid * 336;
    const float4* w1 = W + (size_t)(1024 + wid) * 336;
    const float4* w2 = W + (size_t)(2048 + wid) * 336;
    const float4* x4 = (const float4*)xfc1;
    const float4* sx4 = (const float4*)sx;      // 80 float4
    float ai0 = 0.f, ai1 = 0.f, ai2 = 0.f, ah0 = 0.f, ah1 = 0.f, ah2 = 0.f;
#pragma unroll
    for (int i = 0; i < 4; ++i) {
        int k = lane + (i << 6);
        float4 xv = x4[k];
        ai0 += dot4(w0[k], xv); ai1 += dot4(w1[k], xv); ai2 += dot4(w2[k], xv);
    }
    {
        int k = 256 + lane;                     // lanes 0..63 -> sx4[0..63]
        float4 xv = sx4[lane];
        ai0 += dot4(w0[k], xv); ai1 += dot4(w1[k], xv); ai2 += dot4(w2[k], xv);
    }
    if (lane < 16) {
        int k = 320 + lane;
        float4 xv = sx4[64 + lane];
        ai0 += dot4(w0[k], xv); ai1 += dot4(w1[k], xv); ai2 += dot4(w2[k], xv);
    }
    gru_hh(wid, lane, Whh, h, ah0, ah1, ah2);
    gru_tail(wid, lane, ai0, ai1, ai2, ah0, ah1, ah2, bih, bhh, h, out);
}

// -------- wave-per-row matvec + ReLU, compile-time iteration count (K = NITER*256) --------
template <int NITER>
__global__ void k_matvec_relu(const float* __restrict__ W, const float* __restrict__ x,
                              const float* __restrict__ b, float* __restrict__ out) {
    int wid = (blockIdx.x << 2) + (threadIdx.x >> 6);
    int lane = threadIdx.x & 63;
    const float4* w4 = (const float4*)W + (size_t)wid * (NITER * 64);
    const float4* x4 = (const float4*)x;
    float a0 = 0.f, a1 = 0.f;
#pragma unroll
    for (int i = 0; i < NITER; ++i) {
        int k = lane + (i << 6);
        float v = dot4(w4[k], x4[k]);
        if (i & 1) a1 += v; else a0 += v;
    }
    float a = wave_reduce(a0 + a1);
    if (lane == 0) out[wid] = fmaxf(a + b[wid], 0.f);
}

// -------- block-per-row matvec (K = 81920), 512 threads --------
__global__ void k_matvec_big(const float* __restrict__ W, const float* __restrict__ x,
                             const float* __restrict__ b, float* __restrict__ out) {
    int row = blockIdx.x;
    int t = threadIdx.x;
    const float4* w4 = (const float4*)W + (size_t)row * 20480;
    const float4* x4 = (const float4*)x;
    float a0 = 0.f, a1 = 0.f;
#pragma unroll 4
    for (int k = t; k < 20480; k += 512) {
        float v = dot4(w4[k], x4[k]);
        if (k & 512) a1 += v; else a0 += v;
    }
    float a = wave_reduce(a0 + a1);
    __shared__ float s[8];
    if ((t & 63) == 0) s[t >> 6] = a;
    __syncthreads();
    if (t == 0) {
        float r = b[row];
#pragma unroll
        for (int i = 0; i < 8; ++i) r += s[i];
        out[row] = r;
    }
}

// -------- epilogue: out = prior + KG @ (y - H@prior) --------
__global__ void k_final(const float* __restrict__ F, const float* __restrict__ Hm,
                        const float* __restrict__ post, const float* __restrict__ y,
                        const float* __restrict__ kg, float* __restrict__ out) {
    __shared__ float sprior[32], sdy[32];
    int i = threadIdx.x;   // 32
    float p = 0.f;
#pragma unroll
    for (int j = 0; j < 32; ++j) p = fmaf(F[i * 32 + j], post[j], p);
    sprior[i] = p;
    __syncthreads();
    float m = 0.f;
#pragma unroll
    for (int j = 0; j < 32; ++j) m = fmaf(Hm[i * 32 + j], sprior[j], m);
    sdy[i] = y[i] - m;
    __syncthreads();
    float a = sprior[i];
#pragma unroll
    for (int j = 0; j < 32; ++j) a = fmaf(kg[i * 32 + j], sdy[j], a);
    out[i] = a;
}

extern "C" void kernel_launch(void* const* d_in, const int* in_sizes, int n_in,
                              void* d_out, int out_size, void* d_ws, size_t ws_size,
                              hipStream_t stream) {
    const float* y          = (const float*)d_in[0];
    const float* post       = (const float*)d_in[1];
    const float* post_prev  = (const float*)d_in[2];
    const float* prior_prev = (const float*)d_in[3];
    const float* y_prev     = (const float*)d_in[4];
    const float* h_Q        = (const float*)d_in[5];
    const float* h_Sigma    = (const float*)d_in[6];
    const float* h_S        = (const float*)d_in[7];
    const float* F          = (const float*)d_in[8];
    const float* Hm         = (const float*)d_in[9];
    const float* FC5_w      = (const float*)d_in[10];
    const float* FC5_b      = (const float*)d_in[11];
    const float* FC6_w      = (const float*)d_in[12];
    const float* FC6_b      = (const float*)d_in[13];
    const float* FC7_w      = (const float*)d_in[14];
    const float* FC7_b      = (const float*)d_in[15];
    const float* GQ_Wih     = (const float*)d_in[16];
    const float* GQ_Whh     = (const float*)d_in[17];
    const float* GQ_bih     = (const float*)d_in[18];
    const float* GQ_bhh     = (const float*)d_in[19];
    const float* GS_Wih     = (const float*)d_in[20];
    const float* GS_Whh     = (const float*)d_in[21];
    const float* GS_bih     = (const float*)d_in[22];
    const float* GS_bhh     = (const float*)d_in[23];
    const float* GU_Wih     = (const float*)d_in[24];
    const float* GU_Whh     = (const float*)d_in[25];
    const float* GU_bih     = (const float*)d_in[26];
    const float* GU_bhh     = (const float*)d_in[27];
    const float* FC1_w      = (const float*)d_in[28];
    const float* FC1_b      = (const float*)d_in[29];
    const float* FC2_w1     = (const float*)d_in[30];
    const float* FC2_b1     = (const float*)d_in[31];
    const float* FC2_w2     = (const float*)d_in[32];
    const float* FC2_b2     = (const float*)d_in[33];
    // d_in[34..37] = FC3/FC4 (dead); d_in[38] = fix_H_flag (always 1)

    float* ws = (float*)d_ws;

    // 1) GRU_Q (FC5 prologue folded)
    k_gru_q<<<256, 256, 0, stream>>>(post, post_prev, FC5_w, FC5_b, h_Q,
                                     GQ_Wih, GQ_Whh, GQ_bih, GQ_bhh, ws + WS_Q);
    // 2) GRU_Sigma (FC6 prologue folded) -> out_Sigma
    k_gru_sigma<<<256, 256, 0, stream>>>(ws + WS_Q, post, prior_prev, FC6_w, FC6_b, h_Sigma,
                                         GS_Wih, GS_Whh, GS_bih, GS_bhh, ws + WS_SIG);
    // 3) FC1 (K=1024)
    k_matvec_relu<4><<<256, 256, 0, stream>>>(FC1_w, ws + WS_SIG, FC1_b, ws + WS_FC1);
    // 4) GRU_S (m1y + FC7 prologue folded) -> out_S
    k_gru_s<<<256, 256, 0, stream>>>(ws + WS_FC1, y, y_prev, post, F, Hm, FC7_w, FC7_b, h_S,
                                     GU_Wih, GU_Whh, GU_bih, GU_bhh, ws + WS_S);
    // 5) FC2 layer 1 (K=2048), 81920 rows
    k_matvec_relu<8><<<20480, 256, 0, stream>>>(FC2_w1, ws + WS_SIG, FC2_b1, ws + WS_HID);
    // 6) FC2 layer 2 (K=81920), 1024 rows
    k_matvec_big<<<1024, 512, 0, stream>>>(FC2_w2, ws + WS_HID, FC2_b2, ws + WS_KG);
    // 7) epilogue
    k_final<<<1, 32, 0, stream>>>(F, Hm, post, y, ws + WS_KG, (float*)d_out);
}

// Round 4
// 181.936 us; speedup vs baseline: 1.1595x; 1.1302x over previous
//
#include <hip/hip_runtime.h>
#include <math.h>

#define DEV __device__ __forceinline__

typedef float f4 __attribute__((ext_vector_type(4)));

DEV f4 ntl(const f4* p) { return __builtin_nontemporal_load(p); }

DEV float dot4(f4 w, f4 x) {
    float s = 0.f;
    s = fmaf(w.x, x.x, s); s = fmaf(w.y, x.y, s);
    s = fmaf(w.z, x.z, s); s = fmaf(w.w, x.w, s);
    return s;
}

DEV float wave_reduce(float v) {          // 64-lane sum -> lane 0
    for (int off = 32; off > 0; off >>= 1) v += __shfl_down(v, off);
    return v;
}
DEV float reduce32(float v) {             // sum within 32-lane group
    for (int off = 16; off > 0; off >>= 1) v += __shfl_xor(v, off);
    return v;
}

// ---- ws layout (float offsets, all %4==0) ----
#define WS_Q     0        // 1024  out_Q           (x_sigma = ws[0..1184))
#define WS_FC6   1024     // 160   relu(FC6@nd)
#define WS_SIG   1184     // 1024  out_Sigma
#define WS_FC1   2208     // 1024  out_FC1         (x_s = ws[2208..3552))
#define WS_FC7   3232     // 320   relu(FC7@[obs|innov])
#define WS_S     3552     // 1024  out_S
#define WS_HID   4576     // 81920 hid (partial then relu'd)
#define WS_KG    86496    // 1024  KG flat
// total 87520 floats = 350,080 B

// ---- block-per-row GRU core: 256 threads compute one output element ----
template <int K4X>
DEV void gru_row(int row, int t, const float* __restrict__ x,
                 const float* __restrict__ h,
                 const float* __restrict__ Wih, const float* __restrict__ Whh,
                 const float* __restrict__ bih, const float* __restrict__ bhh,
                 float* __restrict__ out) {
    const f4* x4 = (const f4*)x;
    const f4* w0 = (const f4*)Wih + (size_t)row * K4X;
    const f4* w1 = (const f4*)Wih + (size_t)(1024 + row) * K4X;
    const f4* w2 = (const f4*)Wih + (size_t)(2048 + row) * K4X;
    float ai0 = 0.f, ai1 = 0.f, ai2 = 0.f;
    if (K4X >= 256 || t < K4X) {
        f4 xv = x4[t];
        ai0 = dot4(ntl(w0 + t), xv);
        ai1 = dot4(ntl(w1 + t), xv);
        ai2 = dot4(ntl(w2 + t), xv);
    }
    if (K4X > 256) {
        if (t < K4X - 256) {
            int k = 256 + t;
            f4 xv = x4[k];
            ai0 += dot4(ntl(w0 + k), xv);
            ai1 += dot4(ntl(w1 + k), xv);
            ai2 += dot4(ntl(w2 + k), xv);
        }
    }
    const f4* v0 = (const f4*)Whh + (size_t)row * 256;
    const f4* v1 = (const f4*)Whh + (size_t)(1024 + row) * 256;
    const f4* v2 = (const f4*)Whh + (size_t)(2048 + row) * 256;
    f4 hv = ((const f4*)h)[t];
    float ah0 = dot4(ntl(v0 + t), hv);
    float ah1 = dot4(ntl(v1 + t), hv);
    float ah2 = dot4(ntl(v2 + t), hv);
    ai0 = wave_reduce(ai0); ai1 = wave_reduce(ai1); ai2 = wave_reduce(ai2);
    ah0 = wave_reduce(ah0); ah1 = wave_reduce(ah1); ah2 = wave_reduce(ah2);
    __shared__ float red[4][6];
    int w = t >> 6, lane = t & 63;
    if (lane == 0) {
        red[w][0] = ai0; red[w][1] = ai1; red[w][2] = ai2;
        red[w][3] = ah0; red[w][4] = ah1; red[w][5] = ah2;
    }
    __syncthreads();
    if (t == 0) {
        float AI0 = red[0][0] + red[1][0] + red[2][0] + red[3][0];
        float AI1 = red[0][1] + red[1][1] + red[2][1] + red[3][1];
        float AI2 = red[0][2] + red[1][2] + red[2][2] + red[3][2];
        float AH0 = red[0][3] + red[1][3] + red[2][3] + red[3][3];
        float AH1 = red[0][4] + red[1][4] + red[2][4] + red[3][4];
        float AH2 = red[0][5] + red[1][5] + red[2][5] + red[3][5];
        float gr = AI0 + bih[row]        + AH0 + bhh[row];
        float gz = AI1 + bih[row + 1024] + AH1 + bhh[row + 1024];
        float r = 1.f / (1.f + expf(-gr));
        float z = 1.f / (1.f + expf(-gz));
        float n = tanhf(AI2 + bih[row + 2048] + r * (AH2 + bhh[row + 2048]));
        out[row] = (1.f - z) * n + z * h[row];
    }
}

// ---- K1: GRU_Q (blocks 0..1023, FC5 prologue) | FC6 (block 1024) | FC7+priors (block 1025) ----
__global__ __launch_bounds__(256) void k_stage1(
        const float* __restrict__ y, const float* __restrict__ y_prev,
        const float* __restrict__ post, const float* __restrict__ post_prev,
        const float* __restrict__ prior_prev,
        const float* __restrict__ F, const float* __restrict__ Hm,
        const float* __restrict__ fc5w, const float* __restrict__ fc5b,
        const float* __restrict__ fc6w, const float* __restrict__ fc6b,
        const float* __restrict__ fc7w, const float* __restrict__ fc7b,
        const float* __restrict__ h_Q,
        const float* __restrict__ Wih, const float* __restrict__ Whh,
        const float* __restrict__ bih, const float* __restrict__ bhh,
        float* __restrict__ ws) {
    int t = threadIdx.x;
    if (blockIdx.x < 1024) {
        __shared__ __align__(16) float sx[160];
        __shared__ float sd[32];
        __shared__ float sinv;
        if (t < 32) sd[t] = post[t] - post_prev[t];
        __syncthreads();
        if (t < 64) {
            float d = (t < 32) ? sd[t] * sd[t] : 0.f;
            d = wave_reduce(d);
            if (t == 0) sinv = 1.f / fmaxf(sqrtf(d), 1e-12f);
        }
        __syncthreads();
        if (t < 160) {
            float a = 0.f;
#pragma unroll
            for (int j = 0; j < 32; ++j) a = fmaf(fc5w[t * 32 + j], sd[j], a);
            sx[t] = fmaxf(fmaf(a, sinv, fc5b[t]), 0.f);
        }
        __syncthreads();
        gru_row<40>(blockIdx.x, t, sx, h_Q, Wih, Whh, bih, bhh, ws + WS_Q);
    } else if (blockIdx.x == 1024) {
        __shared__ float sd[32];
        __shared__ float sinv;
        if (t < 32) sd[t] = post[t] - prior_prev[t];
        __syncthreads();
        if (t < 64) {
            float d = (t < 32) ? sd[t] * sd[t] : 0.f;
            d = wave_reduce(d);
            if (t == 0) sinv = 1.f / fmaxf(sqrtf(d), 1e-12f);
        }
        __syncthreads();
        if (t < 160) {
            float a = 0.f;
#pragma unroll
            for (int j = 0; j < 32; ++j) a = fmaf(fc6w[t * 32 + j], sd[j], a);
            ws[WS_FC6 + t] = fmaxf(fmaf(a, sinv, fc6b[t]), 0.f);
        }
    } else {
        __shared__ float sp[32], sd0[32], sd1[32];
        __shared__ float sinv0, sinv1;
        if (t < 32) {
            float p = 0.f;
#pragma unroll
            for (int j = 0; j < 32; ++j) p = fmaf(F[t * 32 + j], post[j], p);
            sp[t] = p;
            sd0[t] = y[t] - y_prev[t];
        }
        __syncthreads();
        if (t < 32) {
            float m = 0.f;
#pragma unroll
            for (int j = 0; j < 32; ++j) m = fmaf(Hm[t * 32 + j], sp[j], m);
            sd1[t] = y[t] - m;
        }
        __syncthreads();
        if (t < 64) {
            int g = t >> 5, j = t & 31;
            float d = g ? sd1[j] : sd0[j];
            float s = reduce32(d * d);
            if (j == 0) {
                float inv = 1.f / fmaxf(sqrtf(s), 1e-12f);
                if (g) sinv1 = inv; else sinv0 = inv;
            }
        }
        __syncthreads();
        for (int r = t; r < 320; r += 256) {
            float a0 = 0.f, a1 = 0.f;
#pragma unroll
            for (int j = 0; j < 32; ++j) {
                a0 = fmaf(fc7w[r * 64 + j], sd0[j], a0);
                a1 = fmaf(fc7w[r * 64 + 32 + j], sd1[j], a1);
            }
            ws[WS_FC7 + r] = fmaxf(a0 * sinv0 + a1 * sinv1 + fc7b[r], 0.f);
        }
    }
}

// ---- K2: GRU_Sigma, block-per-row, x = ws[0..1184) ----
__global__ __launch_bounds__(256) void k_stage2(
        const float* __restrict__ h, const float* __restrict__ Wih,
        const float* __restrict__ Whh, const float* __restrict__ bih,
        const float* __restrict__ bhh, float* __restrict__ ws) {
    gru_row<296>(blockIdx.x, threadIdx.x, ws + WS_Q, h, Wih, Whh, bih, bhh, ws + WS_SIG);
}

// ---- streaming W1a wave-per-row helper: partial = W1[wid, 0:1024] @ sigma ----
DEV void w1a_wave(int wid, int t, const float* __restrict__ W1, float* __restrict__ ws) {
    int lane = t & 63;
    const f4* w4 = (const f4*)W1 + (size_t)wid * 512;   // row = 512 f4; first 256 = sigma cols
    const f4* x4 = (const f4*)(ws + WS_SIG);
    float a0 = 0.f, a1 = 0.f;
#pragma unroll
    for (int i = 0; i < 4; ++i) {
        int k = lane + (i << 6);
        float v = dot4(ntl(w4 + k), x4[k]);
        if (i & 1) a1 += v; else a0 += v;
    }
    float a = wave_reduce(a0 + a1);
    if (lane == 0) ws[WS_HID + wid] = a;
}

// ---- K3: FC1 (blocks 0..1023) | W1a rows 0..40959 (blocks 1024..11263) ----
__global__ __launch_bounds__(256) void k_stage3(
        const float* __restrict__ W1, const float* __restrict__ fc1w,
        const float* __restrict__ fc1b, float* __restrict__ ws) {
    int t = threadIdx.x;
    if (blockIdx.x < 1024) {
        int row = blockIdx.x;
        const f4* w4 = (const f4*)fc1w + (size_t)row * 256;
        const f4* x4 = (const f4*)(ws + WS_SIG);
        float a = dot4(ntl(w4 + t), x4[t]);
        a = wave_reduce(a);
        __shared__ float s[4];
        if ((t & 63) == 0) s[t >> 6] = a;
        __syncthreads();
        if (t == 0) ws[WS_FC1 + row] = fmaxf(s[0] + s[1] + s[2] + s[3] + fc1b[row], 0.f);
    } else {
        int wid = ((blockIdx.x - 1024) << 2) + (t >> 6);        // 0..40959
        w1a_wave(wid, t, W1, ws);
    }
}

// ---- K4: GRU_S (blocks 0..1023) | W1a rows 40960..81919 ----
__global__ __launch_bounds__(256) void k_stage4(
        const float* __restrict__ W1, const float* __restrict__ h,
        const float* __restrict__ Wih, const float* __restrict__ Whh,
        const float* __restrict__ bih, const float* __restrict__ bhh,
        float* __restrict__ ws) {
    int t = threadIdx.x;
    if (blockIdx.x < 1024) {
        gru_row<336>(blockIdx.x, t, ws + WS_FC1, h, Wih, Whh, bih, bhh, ws + WS_S);
    } else {
        int wid = 40960 + ((blockIdx.x - 1024) << 2) + (t >> 6);
        w1a_wave(wid, t, W1, ws);
    }
}

// ---- K5: hid = relu(partial + W1[:,1024:2048] @ out_S + b1) ----
__global__ __launch_bounds__(256) void k_w1b(
        const float* __restrict__ W1, const float* __restrict__ b1,
        float* __restrict__ ws) {
    int wid = (blockIdx.x << 2) + (threadIdx.x >> 6);
    int lane = threadIdx.x & 63;
    const f4* w4 = (const f4*)W1 + (size_t)wid * 512 + 256;     // cols 1024..2047
    const f4* x4 = (const f4*)(ws + WS_S);
    float a0 = 0.f, a1 = 0.f;
#pragma unroll
    for (int i = 0; i < 4; ++i) {
        int k = lane + (i << 6);
        float v = dot4(ntl(w4 + k), x4[k]);
        if (i & 1) a1 += v; else a0 += v;
    }
    float a = wave_reduce(a0 + a1);
    if (lane == 0) ws[WS_HID + wid] = fmaxf(ws[WS_HID + wid] + a + b1[wid], 0.f);
}

// ---- K6: KG = W2 @ hid + b2 (block-per-row, 512 threads) ----
__global__ __launch_bounds__(512) void k_w2(
        const float* __restrict__ W2, const float* __restrict__ b2,
        float* __restrict__ ws) {
    int row = blockIdx.x;
    int t = threadIdx.x;
    const f4* w4 = (const f4*)W2 + (size_t)row * 20480;
    const f4* x4 = (const f4*)(ws + WS_HID);
    float a0 = 0.f, a1 = 0.f;
#pragma unroll 4
    for (int k = t; k < 20480; k += 512) {
        float v = dot4(ntl(w4 + k), x4[k]);
        if (k & 512) a1 += v; else a0 += v;
    }
    float a = wave_reduce(a0 + a1);
    __shared__ float s[8];
    if ((t & 63) == 0) s[t >> 6] = a;
    __syncthreads();
    if (t == 0) {
        float r = b2[row];
#pragma unroll
        for (int i = 0; i < 8; ++i) r += s[i];
        ws[WS_KG + row] = r;
    }
}

// ---- K7: out = prior + KG @ (y - H@prior) ----
__global__ void k_final(const float* __restrict__ F, const float* __restrict__ Hm,
                        const float* __restrict__ post, const float* __restrict__ y,
                        const float* __restrict__ kg, float* __restrict__ out) {
    __shared__ float sprior[32], sdy[32];
    int i = threadIdx.x;   // 32
    float p = 0.f;
#pragma unroll
    for (int j = 0; j < 32; ++j) p = fmaf(F[i * 32 + j], post[j], p);
    sprior[i] = p;
    __syncthreads();
    float m = 0.f;
#pragma unroll
    for (int j = 0; j < 32; ++j) m = fmaf(Hm[i * 32 + j], sprior[j], m);
    sdy[i] = y[i] - m;
    __syncthreads();
    float a = sprior[i];
#pragma unroll
    for (int j = 0; j < 32; ++j) a = fmaf(kg[i * 32 + j], sdy[j], a);
    out[i] = a;
}

extern "C" void kernel_launch(void* const* d_in, const int* in_sizes, int n_in,
                              void* d_out, int out_size, void* d_ws, size_t ws_size,
                              hipStream_t stream) {
    const float* y          = (const float*)d_in[0];
    const float* post       = (const float*)d_in[1];
    const float* post_prev  = (const float*)d_in[2];
    const float* prior_prev = (const float*)d_in[3];
    const float* y_prev     = (const float*)d_in[4];
    const float* h_Q        = (const float*)d_in[5];
    const float* h_Sigma    = (const float*)d_in[6];
    const float* h_S        = (const float*)d_in[7];
    const float* F          = (const float*)d_in[8];
    const float* Hm         = (const float*)d_in[9];
    const float* FC5_w      = (const float*)d_in[10];
    const float* FC5_b      = (const float*)d_in[11];
    const float* FC6_w      = (const float*)d_in[12];
    const float* FC6_b      = (const float*)d_in[13];
    const float* FC7_w      = (const float*)d_in[14];
    const float* FC7_b      = (const float*)d_in[15];
    const float* GQ_Wih     = (const float*)d_in[16];
    const float* GQ_Whh     = (const float*)d_in[17];
    const float* GQ_bih     = (const float*)d_in[18];
    const float* GQ_bhh     = (const float*)d_in[19];
    const float* GS_Wih     = (const float*)d_in[20];
    const float* GS_Whh     = (const float*)d_in[21];
    const float* GS_bih     = (const float*)d_in[22];
    const float* GS_bhh     = (const float*)d_in[23];
    const float* GU_Wih     = (const float*)d_in[24];
    const float* GU_Whh     = (const float*)d_in[25];
    const float* GU_bih     = (const float*)d_in[26];
    const float* GU_bhh     = (const float*)d_in[27];
    const float* FC1_w      = (const float*)d_in[28];
    const float* FC1_b      = (const float*)d_in[29];
    const float* FC2_w1     = (const float*)d_in[30];
    const float* FC2_b1     = (const float*)d_in[31];
    const float* FC2_w2     = (const float*)d_in[32];
    const float* FC2_b2     = (const float*)d_in[33];
    // d_in[34..37] = FC3/FC4 (dead); d_in[38] = fix_H_flag (always 1)

    float* ws = (float*)d_ws;

    // K1: GRU_Q | FC6 | FC7 (+prior/m1y)
    k_stage1<<<1026, 256, 0, stream>>>(y, y_prev, post, post_prev, prior_prev, F, Hm,
                                       FC5_w, FC5_b, FC6_w, FC6_b, FC7_w, FC7_b,
                                       h_Q, GQ_Wih, GQ_Whh, GQ_bih, GQ_bhh, ws);
    // K2: GRU_Sigma
    k_stage2<<<1024, 256, 0, stream>>>(h_Sigma, GS_Wih, GS_Whh, GS_bih, GS_bhh, ws);
    // K3: FC1 || W1a rows 0..40959
    k_stage3<<<11264, 256, 0, stream>>>(FC2_w1, FC1_w, FC1_b, ws);
    // K4: GRU_S || W1a rows 40960..81919
    k_stage4<<<11264, 256, 0, stream>>>(FC2_w1, h_S, GU_Wih, GU_Whh, GU_bih, GU_bhh, ws);
    // K5: hid = relu(partial + W1b @ out_S + b1)
    k_w1b<<<20480, 256, 0, stream>>>(FC2_w1, FC2_b1, ws);
    // K6: KG = W2 @ hid + b2
    k_w2<<<1024, 512, 0, stream>>>(FC2_w2, FC2_b2, ws);
    // K7: epilogue
    k_final<<<1, 32, 0, stream>>>(F, Hm, post, y, ws + WS_KG, (float*)d_out);
}